// Round 1
// baseline (32.142 us; speedup 1.0000x reference)
//
#include <hip/hip_runtime.h>
#include <math.h>

#define B_   512
#define C_   10
#define HW_  4096
#define NT   512        // threads per block
#define NWIN 3969       // 63*63 windows
#define NBMP 313        // ceil(10000/32) bitmap words

// Block-wide sum; result valid on tid==0 only. sp must be shared float[NT/64].
__device__ __forceinline__ float block_sum(float v, volatile float* sp, int tid) {
#pragma unroll
    for (int off = 32; off > 0; off >>= 1) v += __shfl_down(v, off, 64);
    __syncthreads();                    // protect sp reuse across calls
    if ((tid & 63) == 0) sp[tid >> 6] = v;
    __syncthreads();
    float s = 0.f;
    if (tid == 0) {
#pragma unroll
        for (int i = 0; i < NT / 64; ++i) s += sp[i];
    }
    return s;
}

__global__ __launch_bounds__(NT, 4) void loss_main(
    const float* __restrict__ pred, const int* __restrict__ tgt,
    const int* __restrict__ inp, const float* __restrict__ strat,
    float* __restrict__ ws)
{
    const int b   = blockIdx.x;
    const int tid = threadIdx.x;

    __shared__ unsigned char s_pred[HW_];
    __shared__ unsigned int  s_bmp[NBMP];
    __shared__ unsigned char s_col[C_];
    __shared__ float         s_red[NT / 64];

    for (int i = tid; i < NBMP; i += NT) s_bmp[i] = 0u;
    if (tid < C_) s_col[tid] = 0;
    __syncthreads();

    const float* pb = pred + (size_t)b * C_ * HW_;
    const int*   tb = tgt + b * HW_;
    const int*   ib = inp + b * HW_;

    float focal = 0.f;
    int eqc = 0, dfc = 0;

#pragma unroll
    for (int k = 0; k < 2; ++k) {
        const int p = (k * NT + tid) * 4;
        const int4 t4 = *(const int4*)(tb + p);
        const int4 i4 = *(const int4*)(ib + p);
        float x[C_][4];
#pragma unroll
        for (int c = 0; c < C_; ++c) {
            const float4 v = *(const float4*)(pb + c * HW_ + p);
            x[c][0] = v.x; x[c][1] = v.y; x[c][2] = v.z; x[c][3] = v.w;
        }
#pragma unroll
        for (int e = 0; e < 4; ++e) {
            const int t  = (e == 0) ? t4.x : (e == 1) ? t4.y : (e == 2) ? t4.z : t4.w;
            const int iv = (e == 0) ? i4.x : (e == 1) ? i4.y : (e == 2) ? i4.z : i4.w;
            s_col[t] = 1;  // benign race: same value
            float mx = x[0][e]; int am = 0;
#pragma unroll
            for (int c = 1; c < C_; ++c) {
                if (x[c][e] > mx) { mx = x[c][e]; am = c; }  // strict > keeps first max
            }
            float se = 0.f, ext = 0.f, xt = 0.f;
#pragma unroll
            for (int c = 0; c < C_; ++c) {
                const float ee = __expf(x[c][e] - mx);
                se += ee;
                if (c == t) { ext = ee; xt = x[c][e]; }
            }
            const float lse = mx + __logf(se);
            const float ce  = lse - xt;          // -log_softmax at target
            const float pt  = ext / se;          // exp(-ce)
            const float om  = 1.f - pt;
            focal += om * om * ce;
            eqc += (am == t);
            dfc += (am != iv);
            s_pred[p + e] = (unsigned char)am;
        }
    }

    // creativity (sigmoid of strategic_reasoning), 128 per b
    float cre = 0.f;
    if (tid < 128) {
        const float sv = strat[b * 128 + tid];
        cre = 1.f / (1.f + __expf(-sv));
    }

    __syncthreads();  // s_pred / s_col complete

    // pattern diversity: 2x2 window codes -> presence bitmap
    for (int idx = tid; idx < NWIN; idx += NT) {
        const int r = idx / 63;
        const int c = idx - r * 63;
        const int base = r * 64 + c;
        const unsigned code = (unsigned)s_pred[base]      * 1000u
                            + (unsigned)s_pred[base + 1]  * 100u
                            + (unsigned)s_pred[base + 64] * 10u
                            + (unsigned)s_pred[base + 65];
        atomicOr(&s_bmp[code >> 5], 1u << (code & 31u));
    }
    __syncthreads();
    int nu = 0;
    if (tid < NBMP) nu = __popc(s_bmp[tid]);

    const float focal_t = block_sum(focal, s_red, tid);
    const float eq_t    = block_sum((float)eqc, s_red, tid);
    const float df_t    = block_sum((float)dfc, s_red, tid);
    const float nu_t    = block_sum((float)nu, s_red, tid);
    const float cre_t   = block_sum(cre, s_red, tid);

    if (tid == 0) {
        int uc = 0;
#pragma unroll
        for (int c = 0; c < C_; ++c) uc += s_col[c];
        const float w = (uc > 3) ? 1.2f : 1.0f;   // strategic weight
        ws[0 * B_ + b] = focal_t * w;
        ws[1 * B_ + b] = eq_t;                                  // intersection
        ws[2 * B_ + b] = (eq_t == 4096.f) ? 1.f : 0.f;          // exact strict
        ws[3 * B_ + b] = (df_t == 0.f) ? 1.f : 0.f;             // copy flag
        ws[4 * B_ + b] = nu_t;                                  // unique codes
        ws[5 * B_ + b] = cre_t;                                 // sigmoid sum
    }
}

__global__ __launch_bounds__(NT) void loss_final(
    const float* __restrict__ ws, float* __restrict__ out)
{
    const int tid = threadIdx.x;  // == b
    __shared__ float s_red[NT / 64];

    const float focal_b = ws[0 * B_ + tid];
    const float inter   = ws[1 * B_ + tid];
    const float strict  = ws[2 * B_ + tid];
    const float copyf   = ws[3 * B_ + tid];
    const float nu      = ws[4 * B_ + tid];
    const float cre     = ws[5 * B_ + tid];

    const float iou  = inter * (1.f / 4096.f);
    const float comb = 0.2f * strict + 0.8f * iou;
    const float divb = nu * (1.f / 3969.f);

    const float focal_s = block_sum(focal_b, s_red, tid);
    const float comb_s  = block_sum(comb, s_red, tid);
    const float iou_s   = block_sum(iou, s_red, tid);
    const float copy_s  = block_sum(copyf, s_red, tid);
    const float div_s   = block_sum(divb, s_red, tid);
    const float cre_s   = block_sum(cre, s_red, tid);

    if (tid == 0) {
        const float focal_loss        = focal_s / (512.f * 4096.f);
        const float comb_mean         = comb_s / 512.f;
        const float exact_count       = comb_s;
        const float exact_bonus       = fmaxf(-comb_mean * 5.f, -3.f);
        const float transform_penalty = (copy_s / 512.f) * 0.2f;
        const float creativity        = (cre_s / (512.f * 128.f)) * 0.15f;
        const float diversity         = (div_s / 512.f) * 0.02f;
        const float gcb               = comb_mean * 0.05f;  // grid factor = min(4096/900,1)=1

        float total = focal_loss + transform_penalty + exact_bonus
                    - creativity - diversity - gcb;
        if (isnan(total) || isinf(total)) total = fminf(focal_loss, 10.f);

        out[0] = total;
        out[1] = focal_loss;
        out[2] = transform_penalty;
        out[3] = exact_bonus;
        out[4] = exact_count;
        out[5] = exact_count;   // combined_matches.sum() appears twice
        out[6] = iou_s / 512.f;
        out[7] = creativity;
        out[8] = diversity;
        out[9] = gcb;
    }
}

extern "C" void kernel_launch(void* const* d_in, const int* in_sizes, int n_in,
                              void* d_out, int out_size, void* d_ws, size_t ws_size,
                              hipStream_t stream)
{
    const float* pred  = (const float*)d_in[0];
    const int*   tgt   = (const int*)d_in[1];
    const int*   inp   = (const int*)d_in[2];
    const float* strat = (const float*)d_in[3];
    float* ws  = (float*)d_ws;
    float* out = (float*)d_out;

    hipLaunchKernelGGL(loss_main, dim3(B_), dim3(NT), 0, stream,
                       pred, tgt, inp, strat, ws);
    hipLaunchKernelGGL(loss_final, dim3(1), dim3(NT), 0, stream, ws, out);
}